// Round 9
// baseline (1804.524 us; speedup 1.0000x reference)
//
#include <hip/hip_runtime.h>
#include <hip/hip_bf16.h>
#include <math.h>

// HebbianPlasticLayer: B=DIN=DOUT=4096, fp32 in/out.
// out = y + eta*tanh(y)*s,  y = x@W.T + bias,  s = (x*x/||x||)@sigmoid(alpha).T
// Round 15: R13 measured 233us/52.7% MfmaUtil (prediction matched). Remaining
// gap vs 132us MFMA floor = LDS co-binding + 1 block/CU latency exposure.
// This round: A-side operands (X, P8) leave LDS -- MFMA A-fragments are
// per-lane 16B global loads (row=l16, chunk=quad) from row-major buffers:
//   - LDS 144->48 KB (sW+sA only) -> 2 blocks/CU resident, 4 waves/SIMD
//   - 1 barrier per K-step (only sW/sA publication)
//   - LDS cyc/block-step ~2900 -> ~1400 (under MFMA 2483)
//   - fp8 pairing: p = 4x dwordx4 (lo/hi 8B halves), q = 4x ds_read_b128
//     (slot-pair (2q)^(r&6) swizzle preserves pair order) -- 32 fp8 MFMA
//   - direct-load waits: compiler-counted vmcnt (it tracks global_load_lds in
//     the same queue); manual VMCNT(0) only at staging publication, fenced.
// Also: conv kernels merged into one launch.

typedef __attribute__((ext_vector_type(4))) float floatx4;
typedef __attribute__((ext_vector_type(8))) short shortx8;
typedef __attribute__((ext_vector_type(4))) int intx4;
typedef __attribute__((ext_vector_type(2))) long longx2;

#define MAT_N 4096
#define MAT_ELEMS ((size_t)MAT_N * MAT_N)

__device__ __forceinline__ unsigned short f2bf(float f) {
    unsigned int u = __float_as_uint(f);
    unsigned int r = (u + 0x7fffu + ((u >> 16) & 1u)) >> 16;   // RNE
    return (unsigned short)r;
}

__device__ __forceinline__ void gload_lds16(const void* gptr, void* lptr) {
    __builtin_amdgcn_global_load_lds(
        (const __attribute__((address_space(1))) unsigned int*)gptr,
        (__attribute__((address_space(3))) unsigned int*)lptr,
        16, 0, 0);
}

__device__ __forceinline__ unsigned lds_off(const void* p) {
    return (unsigned)(unsigned long long)(const __attribute__((address_space(3))) char*)p;
}

template <int OFF>
__device__ __forceinline__ intx4 ldsb128(unsigned addr) {
    intx4 d;
    asm volatile("ds_read_b128 %0, %1 offset:%2" : "=v"(d) : "v"(addr), "i"(OFF));
    return d;
}

// rule #18: MFMA hoists past asm lgkmcnt despite "memory" -> sched_barrier(0)
#define LGKM0() do { asm volatile("s_waitcnt lgkmcnt(0)" ::: "memory"); \
                     __builtin_amdgcn_sched_barrier(0); } while (0)
#define VMCNT(n) asm volatile("s_waitcnt vmcnt(" #n ")" ::: "memory")
#define BARRIER() do { asm volatile("" ::: "memory"); \
                       __builtin_amdgcn_s_barrier(); \
                       asm volatile("" ::: "memory"); } while (0)

// ---------- merged conversion kernel ----------
// blocks [0,4096): xb = bf16(x), p8 = fp8(x^2), sumsq[row] += x^2
// blocks [4096,8192): wb = bf16(W), a8 = fp8(sigmoid(alpha))
__global__ __launch_bounds__(512) void conv_kernel(const float* __restrict__ x,
                                                   const float* __restrict__ W,
                                                   const float* __restrict__ alpha,
                                                   unsigned short* __restrict__ xb,
                                                   unsigned char* __restrict__ p8,
                                                   unsigned short* __restrict__ wb,
                                                   unsigned char* __restrict__ a8,
                                                   float* __restrict__ sumsq) {
    int bid = blockIdx.x;
    if (bid < 4096) {
        size_t base = ((size_t)bid * 512 + threadIdx.x) * 8;
        const float4* xp = (const float4*)(x + base);
        float4 a = xp[0], b = xp[1];
        float v[8] = {a.x, a.y, a.z, a.w, b.x, b.y, b.z, b.w};
        shortx8 xo;
        float sq[8];
        float s = 0.f;
#pragma unroll
        for (int j = 0; j < 8; j++) {
            xo[j] = (short)f2bf(v[j]);
            sq[j] = v[j] * v[j];
            s += sq[j];
        }
        *(shortx8*)(xb + base) = xo;
        int p0 = __builtin_amdgcn_cvt_pk_fp8_f32(sq[0], sq[1], 0, false);
        p0 = __builtin_amdgcn_cvt_pk_fp8_f32(sq[2], sq[3], p0, true);
        int p1 = __builtin_amdgcn_cvt_pk_fp8_f32(sq[4], sq[5], 0, false);
        p1 = __builtin_amdgcn_cvt_pk_fp8_f32(sq[6], sq[7], p1, true);
        int2 pv = {p0, p1};
        *(int2*)(p8 + base) = pv;
        for (int off = 32; off > 0; off >>= 1) s += __shfl_down(s, off, 64);
        if ((threadIdx.x & 63) == 0) atomicAdd(&sumsq[base >> 12], s);
    } else {
        bid -= 4096;
        size_t base = ((size_t)bid * 512 + threadIdx.x) * 8;
        const float4* wp = (const float4*)(W + base);
        const float4* ap = (const float4*)(alpha + base);
        float4 w0 = wp[0], w1 = wp[1], a0 = ap[0], a1 = ap[1];
        float wv[8] = {w0.x, w0.y, w0.z, w0.w, w1.x, w1.y, w1.z, w1.w};
        float av[8] = {a0.x, a0.y, a0.z, a0.w, a1.x, a1.y, a1.z, a1.w};
        shortx8 wo;
        float sg[8];
#pragma unroll
        for (int j = 0; j < 8; j++) {
            wo[j] = (short)f2bf(wv[j]);
            sg[j] = 1.0f / (1.0f + __expf(-av[j]));
        }
        *(shortx8*)(wb + base) = wo;
        int p0 = __builtin_amdgcn_cvt_pk_fp8_f32(sg[0], sg[1], 0, false);
        p0 = __builtin_amdgcn_cvt_pk_fp8_f32(sg[2], sg[3], p0, true);
        int p1 = __builtin_amdgcn_cvt_pk_fp8_f32(sg[4], sg[5], 0, false);
        p1 = __builtin_amdgcn_cvt_pk_fp8_f32(sg[6], sg[7], p1, true);
        int2 pv = {p0, p1};
        *(int2*)(a8 + base) = pv;
    }
}

// ---------- fused dual-GEMM: A-side direct-from-global, 1 barrier/K-step ----------
// sW: bf16 rows 128B, 16B-chunk swizzle kc' = kc ^ (row&7) via pre-swizzled src.
// sA: fp8 rows 64B, 8B-slot swizzle slot' = slot ^ (row&6); b128 reads the
// slot PAIR (2q)^(r&6) -> global pair (2q,2q+1) in order (r&6 even).
__global__ __launch_bounds__(512, 4) void fused_gemm_kernel(
    const unsigned short* __restrict__ X,
    const unsigned short* __restrict__ Wb,
    const unsigned char* __restrict__ P8,
    const unsigned char* __restrict__ A8,
    const float* __restrict__ bias,
    const float* __restrict__ eta_p,
    const float* __restrict__ sumsq,
    float* __restrict__ out) {
    constexpr int K = MAT_N;
    constexpr int N = MAT_N;
    __shared__ __align__(16) unsigned short sW[2][128 * 64];  // 32 KB
    __shared__ __align__(16) unsigned char  sA[2][128 * 64];  // 16 KB

    const int tid = threadIdx.x;
    const int row0 = blockIdx.y * 256;
    const int col0 = blockIdx.x * 128;
    const int lane = tid & 63;
    const int wave = tid >> 6;           // 0..7
    const int wm = (wave >> 1) * 64;     // 4x2 wave grid: 64-row x 64-col each
    const int wn = (wave & 1) * 64;
    const int quad = lane >> 4;
    const int l16 = lane & 15;

    floatx4 accY[4][4], accS[4][4];
#pragma unroll
    for (int i = 0; i < 4; i++)
#pragma unroll
        for (int j = 0; j < 4; j++) {
            accY[i][j] = (floatx4){0.f, 0.f, 0.f, 0.f};
            accS[i][j] = (floatx4){0.f, 0.f, 0.f, 0.f};
        }

    // W staging: per 64-row segment, thread t -> row t>>3, chunk (t&7)^(row&7)
    const int rs  = tid >> 3;
    const int kcg = (tid & 7) ^ (rs & 7);
    const size_t wrow = (size_t)(col0 + rs) * K + (size_t)kcg * 8;
    // A8 staging: thread t -> row t>>2, slot pair (2(t&3))^(row&6)
    const int r8 = tid >> 2;
    const int s8 = (2 * (tid & 3)) ^ (r8 & 6);
    const size_t arow = (size_t)(col0 + r8) * K + (size_t)s8 * 8;

    const unsigned sw0 = lds_off(&sW[0][0]);
    const unsigned sa0 = lds_off(&sA[0][0]);

#define PF_W(SEG, BUF, KP) gload_lds16(Wb + wrow + (size_t)(SEG) * 64 * K + (KP), &sW[BUF][(SEG) * 4096 + tid * 8])
#define PF_A8(BUF, KP)     gload_lds16(A8 + arow + (KP), &sA[BUF][tid * 16])

    // direct A-side bases: this wave's rows (row0+wm+l16), fragment i adds 16 rows
    const unsigned short* xr = X + (size_t)(row0 + wm + l16) * K;
    const unsigned char*  pr = P8 + (size_t)(row0 + wm + l16) * K;

    // prologue: stage W/A K-step 0 into buf 0
    PF_W(0, 0, 0); PF_W(1, 0, 0);
    PF_A8(0, 0);
    VMCNT(0);
    BARRIER();

    const unsigned kcp0 = (unsigned)(((0 * 4 + quad) ^ (l16 & 7)) * 16);
    const unsigned kcp1 = (unsigned)(((1 * 4 + quad) ^ (l16 & 7)) * 16);
    const unsigned qsw  = (unsigned)(((2 * quad) ^ (l16 & 6)) * 8);

    for (int t = 0; t < 64; ++t) {
        const int cur = t & 1;
        const int nx = cur ^ 1;
        const size_t kp = (size_t)((t + 1) & 63) * 64;  // wrap keeps counts uniform
        const unsigned swc = sw0 + (unsigned)cur * (128 * 64 * 2);
        const unsigned sac = sa0 + (unsigned)cur * (128 * 64);
        const size_t kx = (size_t)t * 64;               // k elem offset (bf16/fp8)

        // ---------------- ph0: Y . slice0 ----------------
        {
            intx4 a0[4], b0[4];
#pragma unroll
            for (int i = 0; i < 4; ++i)
                a0[i] = *(const intx4*)(xr + (size_t)i * 16 * K + kx + quad * 8);
            const unsigned bx = swc + (unsigned)(wn + l16) * 128 + kcp0;
            b0[0] = ldsb128<0>(bx); b0[1] = ldsb128<2048>(bx);
            b0[2] = ldsb128<4096>(bx); b0[3] = ldsb128<6144>(bx);
            PF_W(0, nx, kp); PF_W(1, nx, kp);
            LGKM0();
            __builtin_amdgcn_s_setprio(1);
#pragma unroll
            for (int i = 0; i < 4; ++i)
#pragma unroll
                for (int j = 0; j < 4; ++j)
                    accY[i][j] = __builtin_amdgcn_mfma_f32_16x16x32_bf16(
                        __builtin_bit_cast(shortx8, a0[i]),
                        __builtin_bit_cast(shortx8, b0[j]), accY[i][j], 0, 0, 0);
            __builtin_amdgcn_s_setprio(0);
            __builtin_amdgcn_sched_barrier(0);
        }
        // ---------------- ph1: Y . slice1 ----------------
        intx4 p[4];
        {
            intx4 a1[4], b1[4];
#pragma unroll
            for (int i = 0; i < 4; ++i)
                a1[i] = *(const intx4*)(xr + (size_t)i * 16 * K + kx + 32 + quad * 8);
#pragma unroll
            for (int i = 0; i < 4; ++i)
                p[i] = *(const intx4*)(pr + (size_t)i * 16 * K + kx + quad * 16);
            const unsigned bx = swc + (unsigned)(wn + l16) * 128 + kcp1;
            b1[0] = ldsb128<0>(bx); b1[1] = ldsb128<2048>(bx);
            b1[2] = ldsb128<4096>(bx); b1[3] = ldsb128<6144>(bx);
            PF_A8(nx, kp);
            LGKM0();
            __builtin_amdgcn_s_setprio(1);
#pragma unroll
            for (int i = 0; i < 4; ++i)
#pragma unroll
                for (int j = 0; j < 4; ++j)
                    accY[i][j] = __builtin_amdgcn_mfma_f32_16x16x32_bf16(
                        __builtin_bit_cast(shortx8, a1[i]),
                        __builtin_bit_cast(shortx8, b1[j]), accY[i][j], 0, 0, 0);
            __builtin_amdgcn_s_setprio(0);
            __builtin_amdgcn_sched_barrier(0);
        }
        // ---------------- phS: S (k lo/hi halves, 32 fp8 MFMA) ----------------
        {
            intx4 q[4];
            const unsigned qx = sac + (unsigned)(wn + l16) * 64 + qsw;
            q[0] = ldsb128<0>(qx); q[1] = ldsb128<1024>(qx);
            q[2] = ldsb128<2048>(qx); q[3] = ldsb128<3072>(qx);
            LGKM0();
            __builtin_amdgcn_s_setprio(1);
#pragma unroll
            for (int i = 0; i < 4; ++i) {
                const longx2 pv = __builtin_bit_cast(longx2, p[i]);
#pragma unroll
                for (int j = 0; j < 4; ++j) {
                    const longx2 qv = __builtin_bit_cast(longx2, q[j]);
                    accS[i][j] = __builtin_amdgcn_mfma_f32_16x16x32_fp8_fp8(
                        pv.x, qv.x, accS[i][j], 0, 0, 0);
                    accS[i][j] = __builtin_amdgcn_mfma_f32_16x16x32_fp8_fp8(
                        pv.y, qv.y, accS[i][j], 0, 0, 0);
                }
            }
            __builtin_amdgcn_s_setprio(0);
            __builtin_amdgcn_sched_barrier(0);
            VMCNT(0);   // publish sW/sA staging for t+1 (cross-thread)
            BARRIER();
        }
    }
    VMCNT(0);

    const float eta = *eta_p;
#pragma unroll
    for (int i = 0; i < 4; i++) {
#pragma unroll
        for (int r = 0; r < 4; r++) {
            const int grow = row0 + wm + i * 16 + quad * 4 + r;
            const float invn = 1.0f / (sqrtf(sumsq[grow]) + 1e-8f);
#pragma unroll
            for (int j = 0; j < 4; j++) {
                // C/D layout: row = quad*4 + r, col = lane&15  [m89/m91 verified]
                const int gcol = col0 + wn + j * 16 + l16;
                float y = accY[i][j][r] + bias[gcol];
                float s = accS[i][j][r] * invn;
                out[(size_t)grow * N + gcol] = y + eta * tanhf(y) * s;
            }
        }
    }
}

extern "C" void kernel_launch(void* const* d_in, const int* in_sizes, int n_in,
                              void* d_out, int out_size, void* d_ws, size_t ws_size,
                              hipStream_t stream) {
    const float* x     = (const float*)d_in[0];
    const float* W     = (const float*)d_in[1];
    const float* alpha = (const float*)d_in[2];
    const float* eta   = (const float*)d_in[3];
    const float* bias  = (const float*)d_in[4];
    float* out = (float*)d_out;

    // ws: sumsq f32[4096] (16KB pad) | xb 32MB | wb 32MB | p8 16MB | a8 16MB
    char* ws = (char*)d_ws;
    float* sumsq = (float*)ws;
    unsigned short* xb = (unsigned short*)(ws + 16384);
    unsigned short* wb = xb + MAT_ELEMS;
    unsigned char*  p8 = (unsigned char*)(wb + MAT_ELEMS);
    unsigned char*  a8 = p8 + MAT_ELEMS;

    hipMemsetAsync(sumsq, 0, MAT_N * sizeof(float), stream);
    conv_kernel<<<8192, 512, 0, stream>>>(x, W, alpha, xb, p8, wb, a8, sumsq);

    dim3 grid(MAT_N / 128, MAT_N / 256);   // (N-tiles, M-tiles) = (32, 16)
    fused_gemm_kernel<<<grid, 512, 0, stream>>>(xb, wb, p8, a8, bias, eta, sumsq, out);
}

// Round 10
// 712.730 us; speedup vs baseline: 2.5318x; 2.5318x over previous
//
#include <hip/hip_runtime.h>
#include <hip/hip_bf16.h>
#include <math.h>

// HebbianPlasticLayer: B=DIN=DOUT=4096, fp32 in/out.
// out = y + eta*tanh(y)*s,  y = x@W.T + bias,  s = (x*x/||x||)@sigmoid(alpha).T
// Round 16: R15 regressed 6.9x from REGISTER SPILL (launch_bounds(512,4) capped
// 128 VGPR vs ~230 needed; VGPR_Count=64, WRITE_SIZE=4GB of scratch). The
// dataflow itself was never tested. This round = R15 dataflow at R13's proven
// register budget launch_bounds(512,2):
//   - A-side (X, P8) direct-from-global per-lane 16B fragment loads (no LDS)
//   - LDS 48KB (sW + sA only), 1 barrier per K-step (staging publication)
//   - LDS cyc/block-step ~3100 -> ~1300, under MFMA floor 2483
//   - compiler-inserted counted vmcnt covers a-frag loads; manual counted
//     lgkmcnt only for asm ds_reads (rule #18); one vmcnt(0) pre-barrier
//   - fp8 k-permutation trick: p,q both read as 16B pairs (2quad,2quad+1);
//     same permutation on A and B => positional dot == true dot
// Occupancy stays 2 waves/SIMD (acc footprint), win = LDS+barrier removal.

typedef __attribute__((ext_vector_type(4))) float floatx4;
typedef __attribute__((ext_vector_type(8))) short shortx8;
typedef __attribute__((ext_vector_type(4))) int intx4;
typedef __attribute__((ext_vector_type(2))) long longx2;

#define MAT_N 4096
#define MAT_ELEMS ((size_t)MAT_N * MAT_N)

__device__ __forceinline__ unsigned short f2bf(float f) {
    unsigned int u = __float_as_uint(f);
    unsigned int r = (u + 0x7fffu + ((u >> 16) & 1u)) >> 16;   // RNE
    return (unsigned short)r;
}

__device__ __forceinline__ void gload_lds16(const void* gptr, void* lptr) {
    __builtin_amdgcn_global_load_lds(
        (const __attribute__((address_space(1))) unsigned int*)gptr,
        (__attribute__((address_space(3))) unsigned int*)lptr,
        16, 0, 0);
}

__device__ __forceinline__ unsigned lds_off(const void* p) {
    return (unsigned)(unsigned long long)(const __attribute__((address_space(3))) char*)p;
}

template <int OFF>
__device__ __forceinline__ intx4 ldsb128(unsigned addr) {
    intx4 d;
    asm volatile("ds_read_b128 %0, %1 offset:%2" : "=v"(d) : "v"(addr), "i"(OFF));
    return d;
}

#define SB0() __builtin_amdgcn_sched_barrier(0)
// counted lgkm wait for the asm ds_reads (compiler can't track them) + fence
#define LGKMC(n) do { asm volatile("s_waitcnt lgkmcnt(" #n ")" ::: "memory"); \
                      SB0(); } while (0)
#define VMCNT(n) asm volatile("s_waitcnt vmcnt(" #n ")" ::: "memory")
#define BARRIER() do { asm volatile("" ::: "memory"); \
                       __builtin_amdgcn_s_barrier(); \
                       asm volatile("" ::: "memory"); } while (0)

// ---------- merged conversion kernel ----------
// blocks [0,4096): xb = bf16(x), p8 = fp8(x^2), sumsq[row] += x^2
// blocks [4096,8192): wb = bf16(W), a8 = fp8(sigmoid(alpha))
__global__ __launch_bounds__(512) void conv_kernel(const float* __restrict__ x,
                                                   const float* __restrict__ W,
                                                   const float* __restrict__ alpha,
                                                   unsigned short* __restrict__ xb,
                                                   unsigned char* __restrict__ p8,
                                                   unsigned short* __restrict__ wb,
                                                   unsigned char* __restrict__ a8,
                                                   float* __restrict__ sumsq) {
    int bid = blockIdx.x;
    if (bid < 4096) {
        size_t base = ((size_t)bid * 512 + threadIdx.x) * 8;
        const float4* xp = (const float4*)(x + base);
        float4 a = xp[0], b = xp[1];
        float v[8] = {a.x, a.y, a.z, a.w, b.x, b.y, b.z, b.w};
        shortx8 xo;
        float sq[8];
        float s = 0.f;
#pragma unroll
        for (int j = 0; j < 8; j++) {
            xo[j] = (short)f2bf(v[j]);
            sq[j] = v[j] * v[j];
            s += sq[j];
        }
        *(shortx8*)(xb + base) = xo;
        int p0 = __builtin_amdgcn_cvt_pk_fp8_f32(sq[0], sq[1], 0, false);
        p0 = __builtin_amdgcn_cvt_pk_fp8_f32(sq[2], sq[3], p0, true);
        int p1 = __builtin_amdgcn_cvt_pk_fp8_f32(sq[4], sq[5], 0, false);
        p1 = __builtin_amdgcn_cvt_pk_fp8_f32(sq[6], sq[7], p1, true);
        int2 pv = {p0, p1};
        *(int2*)(p8 + base) = pv;
        for (int off = 32; off > 0; off >>= 1) s += __shfl_down(s, off, 64);
        if ((threadIdx.x & 63) == 0) atomicAdd(&sumsq[base >> 12], s);
    } else {
        bid -= 4096;
        size_t base = ((size_t)bid * 512 + threadIdx.x) * 8;
        const float4* wp = (const float4*)(W + base);
        const float4* ap = (const float4*)(alpha + base);
        float4 w0 = wp[0], w1 = wp[1], a0 = ap[0], a1 = ap[1];
        float wv[8] = {w0.x, w0.y, w0.z, w0.w, w1.x, w1.y, w1.z, w1.w};
        float av[8] = {a0.x, a0.y, a0.z, a0.w, a1.x, a1.y, a1.z, a1.w};
        shortx8 wo;
        float sg[8];
#pragma unroll
        for (int j = 0; j < 8; j++) {
            wo[j] = (short)f2bf(wv[j]);
            sg[j] = 1.0f / (1.0f + __expf(-av[j]));
        }
        *(shortx8*)(wb + base) = wo;
        int p0 = __builtin_amdgcn_cvt_pk_fp8_f32(sg[0], sg[1], 0, false);
        p0 = __builtin_amdgcn_cvt_pk_fp8_f32(sg[2], sg[3], p0, true);
        int p1 = __builtin_amdgcn_cvt_pk_fp8_f32(sg[4], sg[5], 0, false);
        p1 = __builtin_amdgcn_cvt_pk_fp8_f32(sg[6], sg[7], p1, true);
        int2 pv = {p0, p1};
        *(int2*)(a8 + base) = pv;
    }
}

// ---------- fused dual-GEMM: A-side direct-from-global, 1 barrier/K-step ----------
// sW: bf16 rows 128B, 16B-chunk swizzle kc' = kc ^ (row&7) via pre-swizzled src.
// sA: fp8 rows 64B, 8B-slot swizzle slot' = slot ^ (row&6); b128 reads slot
// PAIR (2q)^(r&6) -> global pair (2q,2q+1) in order (r&6 even).
__global__ __launch_bounds__(512, 2) void fused_gemm_kernel(
    const unsigned short* __restrict__ X,
    const unsigned short* __restrict__ Wb,
    const unsigned char* __restrict__ P8,
    const unsigned char* __restrict__ A8,
    const float* __restrict__ bias,
    const float* __restrict__ eta_p,
    const float* __restrict__ sumsq,
    float* __restrict__ out) {
    constexpr int K = MAT_N;
    constexpr int N = MAT_N;
    __shared__ __align__(16) unsigned short sW[2][128 * 64];  // 32 KB
    __shared__ __align__(16) unsigned char  sA[2][128 * 64];  // 16 KB

    const int tid = threadIdx.x;
    const int row0 = blockIdx.y * 256;
    const int col0 = blockIdx.x * 128;
    const int lane = tid & 63;
    const int wave = tid >> 6;           // 0..7
    const int wm = (wave >> 1) * 64;     // 4x2 wave grid: 64-row x 64-col each
    const int wn = (wave & 1) * 64;
    const int quad = lane >> 4;
    const int l16 = lane & 15;

    floatx4 accY[4][4], accS[4][4];
#pragma unroll
    for (int i = 0; i < 4; i++)
#pragma unroll
        for (int j = 0; j < 4; j++) {
            accY[i][j] = (floatx4){0.f, 0.f, 0.f, 0.f};
            accS[i][j] = (floatx4){0.f, 0.f, 0.f, 0.f};
        }

    // W staging: per 64-row segment, thread t -> row t>>3, chunk (t&7)^(row&7)
    const int rs  = tid >> 3;
    const int kcg = (tid & 7) ^ (rs & 7);
    const size_t wrow = (size_t)(col0 + rs) * K + (size_t)kcg * 8;
    // A8 staging: thread t -> row t>>2, slot pair (2(t&3))^(row&6)
    const int r8 = tid >> 2;
    const int s8 = (2 * (tid & 3)) ^ (r8 & 6);
    const size_t arow = (size_t)(col0 + r8) * K + (size_t)s8 * 8;

    const unsigned sw0 = lds_off(&sW[0][0]);
    const unsigned sa0 = lds_off(&sA[0][0]);

#define PF_W(SEG, BUF, KP) gload_lds16(Wb + wrow + (size_t)(SEG) * 64 * K + (KP), &sW[BUF][(SEG) * 4096 + tid * 8])
#define PF_A8(BUF, KP)     gload_lds16(A8 + arow + (KP), &sA[BUF][tid * 16])

    // direct A-side bases: this wave's rows (row0+wm+l16), fragment i adds 16 rows
    const unsigned short* xr = X + (size_t)(row0 + wm + l16) * K;
    const unsigned char*  pr = P8 + (size_t)(row0 + wm + l16) * K;

    // prologue: stage W/A K-step 0 into buf 0
    PF_W(0, 0, 0); PF_W(1, 0, 0);
    PF_A8(0, 0);
    VMCNT(0);
    BARRIER();

    const unsigned kcp0 = (unsigned)(((0 * 4 + quad) ^ (l16 & 7)) * 16);
    const unsigned kcp1 = (unsigned)(((1 * 4 + quad) ^ (l16 & 7)) * 16);
    const unsigned qsw  = (unsigned)(((2 * quad) ^ (l16 & 6)) * 8);

    for (int t = 0; t < 64; ++t) {
        const int cur = t & 1;
        const int nx = cur ^ 1;
        const size_t kp = (size_t)((t + 1) & 63) * 64;  // wrap keeps counts uniform
        const unsigned swc = sw0 + (unsigned)cur * (128 * 64 * 2);
        const unsigned sac = sa0 + (unsigned)cur * (128 * 64);
        const size_t kx = (size_t)t * 64;               // k elem offset

        // A-side direct loads (compiler-tracked vmcnt covers their use)
        intx4 a0[4], a1[4], p[4];
#pragma unroll
        for (int i = 0; i < 4; ++i)
            a0[i] = *(const intx4*)(xr + (size_t)i * 16 * K + kx + quad * 8);
#pragma unroll
        for (int i = 0; i < 4; ++i)
            a1[i] = *(const intx4*)(xr + (size_t)i * 16 * K + kx + 32 + quad * 8);
#pragma unroll
        for (int i = 0; i < 4; ++i)
            p[i] = *(const intx4*)(pr + (size_t)i * 16 * K + kx + quad * 16);
        // staging prefetch for t+1 (drained by vmcnt(0) before the barrier)
        PF_W(0, nx, kp); PF_W(1, nx, kp); PF_A8(nx, kp);

        // LDS reads for ph0+ph1 (8 ds, counted lgkm)
        intx4 b0[4], b1[4];
        {
            const unsigned bx0 = swc + (unsigned)(wn + l16) * 128 + kcp0;
            b0[0] = ldsb128<0>(bx0); b0[1] = ldsb128<2048>(bx0);
            b0[2] = ldsb128<4096>(bx0); b0[3] = ldsb128<6144>(bx0);
            const unsigned bx1 = swc + (unsigned)(wn + l16) * 128 + kcp1;
            b1[0] = ldsb128<0>(bx1); b1[1] = ldsb128<2048>(bx1);
            b1[2] = ldsb128<4096>(bx1); b1[3] = ldsb128<6144>(bx1);
        }
        LGKMC(4);   // b0 done (b1 may be in flight)
        __builtin_amdgcn_s_setprio(1);
#pragma unroll
        for (int i = 0; i < 4; ++i)
#pragma unroll
            for (int j = 0; j < 4; ++j)
                accY[i][j] = __builtin_amdgcn_mfma_f32_16x16x32_bf16(
                    __builtin_bit_cast(shortx8, a0[i]),
                    __builtin_bit_cast(shortx8, b0[j]), accY[i][j], 0, 0, 0);
        __builtin_amdgcn_s_setprio(0);
        SB0();

        // q reads for phS (4 ds) issue under ph1's MFMA
        intx4 q[4];
        {
            const unsigned qx = sac + (unsigned)(wn + l16) * 64 + qsw;
            q[0] = ldsb128<0>(qx); q[1] = ldsb128<1024>(qx);
            q[2] = ldsb128<2048>(qx); q[3] = ldsb128<3072>(qx);
        }
        LGKMC(4);   // b1 done (q may be in flight)
        __builtin_amdgcn_s_setprio(1);
#pragma unroll
        for (int i = 0; i < 4; ++i)
#pragma unroll
            for (int j = 0; j < 4; ++j)
                accY[i][j] = __builtin_amdgcn_mfma_f32_16x16x32_bf16(
                    __builtin_bit_cast(shortx8, a1[i]),
                    __builtin_bit_cast(shortx8, b1[j]), accY[i][j], 0, 0, 0);
        __builtin_amdgcn_s_setprio(0);
        SB0();

        LGKMC(0);   // q done
        __builtin_amdgcn_s_setprio(1);
#pragma unroll
        for (int i = 0; i < 4; ++i) {
            const longx2 pv = __builtin_bit_cast(longx2, p[i]);
#pragma unroll
            for (int j = 0; j < 4; ++j) {
                const longx2 qv = __builtin_bit_cast(longx2, q[j]);
                accS[i][j] = __builtin_amdgcn_mfma_f32_16x16x32_fp8_fp8(
                    pv.x, qv.x, accS[i][j], 0, 0, 0);
                accS[i][j] = __builtin_amdgcn_mfma_f32_16x16x32_fp8_fp8(
                    pv.y, qv.y, accS[i][j], 0, 0, 0);
            }
        }
        __builtin_amdgcn_s_setprio(0);
        SB0();
        VMCNT(0);   // publish sW/sA staging for t+1 (cross-thread)
        BARRIER();
    }
    VMCNT(0);

    const float eta = *eta_p;
#pragma unroll
    for (int i = 0; i < 4; i++) {
#pragma unroll
        for (int r = 0; r < 4; r++) {
            const int grow = row0 + wm + i * 16 + quad * 4 + r;
            const float invn = 1.0f / (sqrtf(sumsq[grow]) + 1e-8f);
#pragma unroll
            for (int j = 0; j < 4; j++) {
                // C/D layout: row = quad*4 + r, col = lane&15  [m89/m91 verified]
                const int gcol = col0 + wn + j * 16 + l16;
                float y = accY[i][j][r] + bias[gcol];
                float s = accS[i][j][r] * invn;
                out[(size_t)grow * N + gcol] = y + eta * tanhf(y) * s;
            }
        }
    }
}

extern "C" void kernel_launch(void* const* d_in, const int* in_sizes, int n_in,
                              void* d_out, int out_size, void* d_ws, size_t ws_size,
                              hipStream_t stream) {
    const float* x     = (const float*)d_in[0];
    const float* W     = (const float*)d_in[1];
    const float* alpha = (const float*)d_in[2];
    const float* eta   = (const float*)d_in[3];
    const float* bias  = (const float*)d_in[4];
    float* out = (float*)d_out;

    // ws: sumsq f32[4096] (16KB pad) | xb 32MB | wb 32MB | p8 16MB | a8 16MB
    char* ws = (char*)d_ws;
    float* sumsq = (float*)ws;
    unsigned short* xb = (unsigned short*)(ws + 16384);
    unsigned short* wb = xb + MAT_ELEMS;
    unsigned char*  p8 = (unsigned char*)(wb + MAT_ELEMS);
    unsigned char*  a8 = p8 + MAT_ELEMS;

    hipMemsetAsync(sumsq, 0, MAT_N * sizeof(float), stream);
    conv_kernel<<<8192, 512, 0, stream>>>(x, W, alpha, xb, p8, wb, a8, sumsq);

    dim3 grid(MAT_N / 128, MAT_N / 256);   // (N-tiles, M-tiles) = (32, 16)
    fused_gemm_kernel<<<grid, 512, 0, stream>>>(xb, wb, p8, a8, bias, eta, sumsq, out);
}

// Round 11
// 446.949 us; speedup vs baseline: 4.0374x; 1.5947x over previous
//
#include <hip/hip_runtime.h>
#include <hip/hip_bf16.h>
#include <math.h>

// HebbianPlasticLayer: B=DIN=DOUT=4096, fp32 in/out.
// out = y + eta*tanh(y)*s,  y = x@W.T + bias,  s = (x*x/||x||)@sigmoid(alpha).T
// Round 17: R16 (A-side direct-from-global) regressed 233->520us: A-frag loads
// had ~0 prefetch distance -> full L2/L3 latency exposed every iter (MfmaUtil
// 21.6%, no spill, 0 conflicts). Register budget can't fit +48 VGPR of A-side
// prefetch next to the 128-reg accumulator. REVERT to the R13 structure
// (best measured: 233us gemm / 52.7% MfmaUtil) + two low-risk deltas:
//   1. phS fp8 reads: 16x ds_read_b64 -> 8x ds_read_b128 via paired k-chunks
//      (2q,2q+1) with the SAME permutation on P and A sides (positional dot ==
//      true dot; numerics proven by R16's passing run).
//   2. Bijective XCD swizzle (T1): f=(bx+by*32); swz=(f&7)*64+(f>>3);
//      each XCD chunk = 2 row-panels x all col-tiles -> X/P L2 reuse.
// Schedule unchanged from R13: ph0 Y.s0 (no barrier) | ph1 Y.s1 + vmcnt(6) +
// barrier | phS S + vmcnt(3) + barrier. Ledger: enter ph0 with 3 fp8-t out;
// ph0 +X012(6); ph1 +X3W01(9)->vmcnt(6); phS +P01A8(9)->vmcnt(3). Never 0.

typedef __attribute__((ext_vector_type(4))) float floatx4;
typedef __attribute__((ext_vector_type(8))) short shortx8;
typedef __attribute__((ext_vector_type(4))) int intx4;
typedef __attribute__((ext_vector_type(2))) long longx2;

#define MAT_N 4096
#define MAT_ELEMS ((size_t)MAT_N * MAT_N)

__device__ __forceinline__ unsigned short f2bf(float f) {
    unsigned int u = __float_as_uint(f);
    unsigned int r = (u + 0x7fffu + ((u >> 16) & 1u)) >> 16;   // RNE
    return (unsigned short)r;
}

__device__ __forceinline__ void gload_lds16(const void* gptr, void* lptr) {
    __builtin_amdgcn_global_load_lds(
        (const __attribute__((address_space(1))) unsigned int*)gptr,
        (__attribute__((address_space(3))) unsigned int*)lptr,
        16, 0, 0);
}

__device__ __forceinline__ unsigned lds_off(const void* p) {
    return (unsigned)(unsigned long long)(const __attribute__((address_space(3))) char*)p;
}

template <int OFF>
__device__ __forceinline__ intx4 ldsb128(unsigned addr) {
    intx4 d;
    asm volatile("ds_read_b128 %0, %1 offset:%2" : "=v"(d) : "v"(addr), "i"(OFF));
    return d;
}

// rule #18: MFMA hoists past asm lgkmcnt despite "memory" -> sched_barrier(0)
#define LGKM0() do { asm volatile("s_waitcnt lgkmcnt(0)" ::: "memory"); \
                     __builtin_amdgcn_sched_barrier(0); } while (0)
#define VMCNT(n) asm volatile("s_waitcnt vmcnt(" #n ")" ::: "memory")
#define BARRIER() do { asm volatile("" ::: "memory"); \
                       __builtin_amdgcn_s_barrier(); \
                       asm volatile("" ::: "memory"); } while (0)

// ---------- merged conversion kernel ----------
// blocks [0,4096): xb = bf16(x), p8 = fp8(x^2), sumsq[row] += x^2
// blocks [4096,8192): wb = bf16(W), a8 = fp8(sigmoid(alpha))
__global__ __launch_bounds__(512) void conv_kernel(const float* __restrict__ x,
                                                   const float* __restrict__ W,
                                                   const float* __restrict__ alpha,
                                                   unsigned short* __restrict__ xb,
                                                   unsigned char* __restrict__ p8,
                                                   unsigned short* __restrict__ wb,
                                                   unsigned char* __restrict__ a8,
                                                   float* __restrict__ sumsq) {
    int bid = blockIdx.x;
    if (bid < 4096) {
        size_t base = ((size_t)bid * 512 + threadIdx.x) * 8;
        const float4* xp = (const float4*)(x + base);
        float4 a = xp[0], b = xp[1];
        float v[8] = {a.x, a.y, a.z, a.w, b.x, b.y, b.z, b.w};
        shortx8 xo;
        float sq[8];
        float s = 0.f;
#pragma unroll
        for (int j = 0; j < 8; j++) {
            xo[j] = (short)f2bf(v[j]);
            sq[j] = v[j] * v[j];
            s += sq[j];
        }
        *(shortx8*)(xb + base) = xo;
        int p0 = __builtin_amdgcn_cvt_pk_fp8_f32(sq[0], sq[1], 0, false);
        p0 = __builtin_amdgcn_cvt_pk_fp8_f32(sq[2], sq[3], p0, true);
        int p1 = __builtin_amdgcn_cvt_pk_fp8_f32(sq[4], sq[5], 0, false);
        p1 = __builtin_amdgcn_cvt_pk_fp8_f32(sq[6], sq[7], p1, true);
        int2 pv = {p0, p1};
        *(int2*)(p8 + base) = pv;
        for (int off = 32; off > 0; off >>= 1) s += __shfl_down(s, off, 64);
        if ((threadIdx.x & 63) == 0) atomicAdd(&sumsq[base >> 12], s);
    } else {
        bid -= 4096;
        size_t base = ((size_t)bid * 512 + threadIdx.x) * 8;
        const float4* wp = (const float4*)(W + base);
        const float4* ap = (const float4*)(alpha + base);
        float4 w0 = wp[0], w1 = wp[1], a0 = ap[0], a1 = ap[1];
        float wv[8] = {w0.x, w0.y, w0.z, w0.w, w1.x, w1.y, w1.z, w1.w};
        float av[8] = {a0.x, a0.y, a0.z, a0.w, a1.x, a1.y, a1.z, a1.w};
        shortx8 wo;
        float sg[8];
#pragma unroll
        for (int j = 0; j < 8; j++) {
            wo[j] = (short)f2bf(wv[j]);
            sg[j] = 1.0f / (1.0f + __expf(-av[j]));
        }
        *(shortx8*)(wb + base) = wo;
        int p0 = __builtin_amdgcn_cvt_pk_fp8_f32(sg[0], sg[1], 0, false);
        p0 = __builtin_amdgcn_cvt_pk_fp8_f32(sg[2], sg[3], p0, true);
        int p1 = __builtin_amdgcn_cvt_pk_fp8_f32(sg[4], sg[5], 0, false);
        p1 = __builtin_amdgcn_cvt_pk_fp8_f32(sg[6], sg[7], p1, true);
        int2 pv = {p0, p1};
        *(int2*)(a8 + base) = pv;
    }
}

// ---------- fused dual-GEMM, 3-phase / 2-barrier counted-vmcnt schedule ----------
// bf16 LDS rows 128B, 16B-chunk swizzle kc' = kc ^ (row&7) (2-way = free).
// fp8 LDS rows 64B, 8B-slot swizzle slot' = slot ^ (row&6); b128 reads the
// slot PAIR (2q)^(r&6) -> global chunks (2q,2q+1) in order (r&6 even).
// All staged via pre-swizzled GLOBAL source; LDS dest stays linear.
__global__ __launch_bounds__(512, 2) void fused_gemm_kernel(
    const unsigned short* __restrict__ X,
    const unsigned short* __restrict__ Wb,
    const unsigned char* __restrict__ P8,
    const unsigned char* __restrict__ A8,
    const float* __restrict__ bias,
    const float* __restrict__ eta_p,
    const float* __restrict__ sumsq,
    float* __restrict__ out) {
    constexpr int K = MAT_N;
    constexpr int N = MAT_N;
    __shared__ __align__(16) unsigned short sX[2][256 * 64];  // 64 KB
    __shared__ __align__(16) unsigned short sW[2][128 * 64];  // 32 KB
    __shared__ __align__(16) unsigned char  sP[2][256 * 64];  // 32 KB
    __shared__ __align__(16) unsigned char  sA[2][128 * 64];  // 16 KB

    const int tid = threadIdx.x;
    // T1 bijective XCD swizzle: 512 wgs, 8 XCDs, 64/XCD; each XCD chunk =
    // 2 row-panels x 32 col-tiles (X/P panel L2 reuse).
    const int f = blockIdx.y * 32 + blockIdx.x;
    const int swz = (f & 7) * 64 + (f >> 3);
    const int row0 = (swz >> 5) * 256;
    const int col0 = (swz & 31) * 128;
    const int lane = tid & 63;
    const int wave = tid >> 6;           // 0..7
    const int wm = (wave >> 1) * 64;     // 4x2 wave grid: 64-row x 64-col each
    const int wn = (wave & 1) * 64;
    const int quad = lane >> 4;
    const int l16 = lane & 15;

    floatx4 accY[4][4], accS[4][4];
#pragma unroll
    for (int i = 0; i < 4; i++)
#pragma unroll
        for (int j = 0; j < 4; j++) {
            accY[i][j] = (floatx4){0.f, 0.f, 0.f, 0.f};
            accS[i][j] = (floatx4){0.f, 0.f, 0.f, 0.f};
        }

    // bf16 staging: per 64-row segment, thread t -> row t>>3, chunk (t&7)^(row&7)
    const int rs  = tid >> 3;
    const int kcg = (tid & 7) ^ (rs & 7);
    const size_t xrow = (size_t)(row0 + rs) * K + (size_t)kcg * 8;
    const size_t wrow = (size_t)(col0 + rs) * K + (size_t)kcg * 8;
    // fp8 staging: per 128-row segment, thread t -> row t>>2, slot (2(t&3))^(row&6)
    const int r8 = tid >> 2;
    const int s8 = (2 * (tid & 3)) ^ (r8 & 6);
    const size_t prow = (size_t)(row0 + r8) * K + (size_t)s8 * 8;
    const size_t arow = (size_t)(col0 + r8) * K + (size_t)s8 * 8;

    const unsigned sx0 = lds_off(&sX[0][0]);
    const unsigned sw0 = lds_off(&sW[0][0]);
    const unsigned sp0 = lds_off(&sP[0][0]);
    const unsigned sa0 = lds_off(&sA[0][0]);

#define PF_X(SEG, BUF, KP) gload_lds16(X + xrow + (size_t)(SEG) * 64 * K + (KP), &sX[BUF][(SEG) * 4096 + tid * 8])
#define PF_W(SEG, BUF, KP) gload_lds16(Wb + wrow + (size_t)(SEG) * 64 * K + (KP), &sW[BUF][(SEG) * 4096 + tid * 8])
#define PF_P(SEG, BUF, KP) gload_lds16(P8 + prow + (size_t)(SEG) * 128 * K + (KP), &sP[BUF][(SEG) * 8192 + tid * 16])
#define PF_A8(BUF, KP)     gload_lds16(A8 + arow + (KP), &sA[BUF][tid * 16])

    // prologue: stage K-step 0 into buf 0 (6 bf16, then 3 fp8)
    PF_X(0, 0, 0); PF_X(1, 0, 0); PF_X(2, 0, 0); PF_X(3, 0, 0);
    PF_W(0, 0, 0); PF_W(1, 0, 0);
    PF_P(0, 0, 0); PF_P(1, 0, 0); PF_A8(0, 0);
    VMCNT(3);          // bf16-0 landed; fp8-0 stays in flight (drained @ph1)
    BARRIER();

    for (int t = 0; t < 64; ++t) {
        const int cur = t & 1;
        const int nx = cur ^ 1;
        const size_t kp = (size_t)((t + 1) & 63) * 64;  // wrap keeps counts uniform
        const unsigned sxc = sx0 + (unsigned)cur * (256 * 64 * 2);
        const unsigned swc = sw0 + (unsigned)cur * (128 * 64 * 2);
        const unsigned spc = sp0 + (unsigned)cur * (256 * 64);
        const unsigned sac = sa0 + (unsigned)cur * (128 * 64);

        // ---------------- ph0: Y . slice0 (no trailing barrier) ----------------
        {
            const unsigned kcp = (unsigned)(((0 * 4 + quad) ^ (l16 & 7)) * 16);
            const unsigned ax = sxc + (unsigned)(wm + l16) * 128 + kcp;
            const unsigned bx = swc + (unsigned)(wn + l16) * 128 + kcp;
            intx4 a[4], b[4];
            a[0] = ldsb128<0>(ax); a[1] = ldsb128<2048>(ax);
            a[2] = ldsb128<4096>(ax); a[3] = ldsb128<6144>(ax);
            b[0] = ldsb128<0>(bx); b[1] = ldsb128<2048>(bx);
            b[2] = ldsb128<4096>(bx); b[3] = ldsb128<6144>(bx);
            PF_X(0, nx, kp); PF_X(1, nx, kp); PF_X(2, nx, kp);
            LGKM0();
            __builtin_amdgcn_s_setprio(1);
#pragma unroll
            for (int i = 0; i < 4; ++i)
#pragma unroll
                for (int j = 0; j < 4; ++j)
                    accY[i][j] = __builtin_amdgcn_mfma_f32_16x16x32_bf16(
                        __builtin_bit_cast(shortx8, a[i]),
                        __builtin_bit_cast(shortx8, b[j]), accY[i][j], 0, 0, 0);
            __builtin_amdgcn_s_setprio(0);
        }
        // ---------------- ph1: Y . slice1 ----------------
        {
            const unsigned kcp = (unsigned)(((1 * 4 + quad) ^ (l16 & 7)) * 16);
            const unsigned ax = sxc + (unsigned)(wm + l16) * 128 + kcp;
            const unsigned bx = swc + (unsigned)(wn + l16) * 128 + kcp;
            intx4 a[4], b[4];
            a[0] = ldsb128<0>(ax); a[1] = ldsb128<2048>(ax);
            a[2] = ldsb128<4096>(ax); a[3] = ldsb128<6144>(ax);
            b[0] = ldsb128<0>(bx); b[1] = ldsb128<2048>(bx);
            b[2] = ldsb128<4096>(bx); b[3] = ldsb128<6144>(bx);
            PF_X(3, nx, kp); PF_W(0, nx, kp); PF_W(1, nx, kp);
            LGKM0();
            __builtin_amdgcn_s_setprio(1);
#pragma unroll
            for (int i = 0; i < 4; ++i)
#pragma unroll
                for (int j = 0; j < 4; ++j)
                    accY[i][j] = __builtin_amdgcn_mfma_f32_16x16x32_bf16(
                        __builtin_bit_cast(shortx8, a[i]),
                        __builtin_bit_cast(shortx8, b[j]), accY[i][j], 0, 0, 0);
            __builtin_amdgcn_s_setprio(0);
            VMCNT(6);   // drains fp8-t (oldest 3); leaves bf16-(t+1) in flight
            BARRIER();
        }
        // ---------------- phS: S paired k-chunks (8 b128, 32 fp8 MFMA) ---------
        {
            const unsigned psw = (unsigned)(((2 * quad) ^ (l16 & 6)) * 8);
            const unsigned px = spc + (unsigned)(wm + l16) * 64 + psw;
            const unsigned qx = sac + (unsigned)(wn + l16) * 64 + psw;
            intx4 p[4], q[4];
            p[0] = ldsb128<0>(px); p[1] = ldsb128<1024>(px);
            p[2] = ldsb128<2048>(px); p[3] = ldsb128<3072>(px);
            q[0] = ldsb128<0>(qx); q[1] = ldsb128<1024>(qx);
            q[2] = ldsb128<2048>(qx); q[3] = ldsb128<3072>(qx);
            PF_P(0, nx, kp); PF_P(1, nx, kp); PF_A8(nx, kp);
            LGKM0();
            __builtin_amdgcn_s_setprio(1);
#pragma unroll
            for (int i = 0; i < 4; ++i) {
                const longx2 pv = __builtin_bit_cast(longx2, p[i]);
#pragma unroll
                for (int j = 0; j < 4; ++j) {
                    const longx2 qv = __builtin_bit_cast(longx2, q[j]);
                    accS[i][j] = __builtin_amdgcn_mfma_f32_16x16x32_fp8_fp8(
                        pv.x, qv.x, accS[i][j], 0, 0, 0);
                    accS[i][j] = __builtin_amdgcn_mfma_f32_16x16x32_fp8_fp8(
                        pv.y, qv.y, accS[i][j], 0, 0, 0);
                }
            }
            __builtin_amdgcn_s_setprio(0);
            VMCNT(3);   // drains bf16-(t+1); leaves fp8-(t+1) in flight
            BARRIER();
        }
    }
    VMCNT(0);   // drain the wrapped tail prefetches before epilogue

    const float eta = *eta_p;
#pragma unroll
    for (int i = 0; i < 4; i++) {
#pragma unroll
        for (int r = 0; r < 4; r++) {
            const int grow = row0 + wm + i * 16 + quad * 4 + r;
            const float invn = 1.0f / (sqrtf(sumsq[grow]) + 1e-8f);
#pragma unroll
            for (int j = 0; j < 4; j++) {
                // C/D layout: row = quad*4 + r, col = lane&15  [m89/m91 verified]
                const int gcol = col0 + wn + j * 16 + l16;
                float y = accY[i][j][r] + bias[gcol];
                float s = accS[i][j][r] * invn;
                out[(size_t)grow * N + gcol] = y + eta * tanhf(y) * s;
            }
        }
    }
}

extern "C" void kernel_launch(void* const* d_in, const int* in_sizes, int n_in,
                              void* d_out, int out_size, void* d_ws, size_t ws_size,
                              hipStream_t stream) {
    const float* x     = (const float*)d_in[0];
    const float* W     = (const float*)d_in[1];
    const float* alpha = (const float*)d_in[2];
    const float* eta   = (const float*)d_in[3];
    const float* bias  = (const float*)d_in[4];
    float* out = (float*)d_out;

    // ws: sumsq f32[4096] (16KB pad) | xb 32MB | wb 32MB | p8 16MB | a8 16MB
    char* ws = (char*)d_ws;
    float* sumsq = (float*)ws;
    unsigned short* xb = (unsigned short*)(ws + 16384);
    unsigned short* wb = xb + MAT_ELEMS;
    unsigned char*  p8 = (unsigned char*)(wb + MAT_ELEMS);
    unsigned char*  a8 = p8 + MAT_ELEMS;

    hipMemsetAsync(sumsq, 0, MAT_N * sizeof(float), stream);
    conv_kernel<<<8192, 512, 0, stream>>>(x, W, alpha, xb, p8, wb, a8, sumsq);

    dim3 grid(MAT_N / 128, MAT_N / 256);   // (N-tiles, M-tiles) = (32, 16)
    fused_gemm_kernel<<<grid, 512, 0, stream>>>(xb, wb, p8, a8, bias, eta, sumsq, out);
}

// Round 13
// 414.873 us; speedup vs baseline: 4.3496x; 1.0773x over previous
//
#include <hip/hip_runtime.h>
#include <hip/hip_bf16.h>
#include <math.h>

// HebbianPlasticLayer: B=DIN=DOUT=4096, fp32 in/out.
// out = y + eta*tanh(y)*s,  y = x@W.T + bias,  s = (x*x/||x||)@sigmoid(alpha).T
// Round 19 (resubmit of Round 18 — broker timeout, never measured):
// R17 attribution -- paired-b128 phS reads: conflicts 8.39M -> 0 (WIN, keep);
// hand XCD swizzle: FETCH 251 -> 427MB, MfmaUtil -10pts (LOSS: default
// dispatch order already shares X-panels across 32 consecutive blocks and
// reuses W-col-panels 8x per XCD L2; my chunking streamed 48MB W per XCD).
// This version = R13 structure + paired-b128 phS ONLY, identity block map.
// Schedule (R13, measured 233us/52.7%): ph0 Y.s0 (no barrier) | ph1 Y.s1 +
// vmcnt(6) + barrier | phS S (8x ds_read_b128 paired k-chunks, 32 fp8 MFMA) +
// vmcnt(3) + barrier. Ledger: enter ph0 with 3 fp8-t out; ph0 +X012(6);
// ph1 +X3W01(9)->vmcnt(6) drains fp8-t; phS +P01A8(9)->vmcnt(3) drains
// bf16-(t+1). Never 0 in-loop.
// fp8 pairing correctness: p and q both read chunk pair (2q,2q+1) under the
// SAME (r&6) swizzle -> identical k-permutation on A and B operands ->
// positional dot == true dot (numerics proven: R16/R17 passed, absmax 0.0469).

typedef __attribute__((ext_vector_type(4))) float floatx4;
typedef __attribute__((ext_vector_type(8))) short shortx8;
typedef __attribute__((ext_vector_type(4))) int intx4;
typedef __attribute__((ext_vector_type(2))) long longx2;

#define MAT_N 4096
#define MAT_ELEMS ((size_t)MAT_N * MAT_N)

__device__ __forceinline__ unsigned short f2bf(float f) {
    unsigned int u = __float_as_uint(f);
    unsigned int r = (u + 0x7fffu + ((u >> 16) & 1u)) >> 16;   // RNE
    return (unsigned short)r;
}

__device__ __forceinline__ void gload_lds16(const void* gptr, void* lptr) {
    __builtin_amdgcn_global_load_lds(
        (const __attribute__((address_space(1))) unsigned int*)gptr,
        (__attribute__((address_space(3))) unsigned int*)lptr,
        16, 0, 0);
}

__device__ __forceinline__ unsigned lds_off(const void* p) {
    return (unsigned)(unsigned long long)(const __attribute__((address_space(3))) char*)p;
}

template <int OFF>
__device__ __forceinline__ intx4 ldsb128(unsigned addr) {
    intx4 d;
    asm volatile("ds_read_b128 %0, %1 offset:%2" : "=v"(d) : "v"(addr), "i"(OFF));
    return d;
}

// rule #18: MFMA hoists past asm lgkmcnt despite "memory" -> sched_barrier(0)
#define LGKM0() do { asm volatile("s_waitcnt lgkmcnt(0)" ::: "memory"); \
                     __builtin_amdgcn_sched_barrier(0); } while (0)
#define VMCNT(n) asm volatile("s_waitcnt vmcnt(" #n ")" ::: "memory")
#define BARRIER() do { asm volatile("" ::: "memory"); \
                       __builtin_amdgcn_s_barrier(); \
                       asm volatile("" ::: "memory"); } while (0)

// ---------- merged conversion kernel ----------
// blocks [0,4096): xb = bf16(x), p8 = fp8(x^2), sumsq[row] += x^2
// blocks [4096,8192): wb = bf16(W), a8 = fp8(sigmoid(alpha))
__global__ __launch_bounds__(512) void conv_kernel(const float* __restrict__ x,
                                                   const float* __restrict__ W,
                                                   const float* __restrict__ alpha,
                                                   unsigned short* __restrict__ xb,
                                                   unsigned char* __restrict__ p8,
                                                   unsigned short* __restrict__ wb,
                                                   unsigned char* __restrict__ a8,
                                                   float* __restrict__ sumsq) {
    int bid = blockIdx.x;
    if (bid < 4096) {
        size_t base = ((size_t)bid * 512 + threadIdx.x) * 8;
        const float4* xp = (const float4*)(x + base);
        float4 a = xp[0], b = xp[1];
        float v[8] = {a.x, a.y, a.z, a.w, b.x, b.y, b.z, b.w};
        shortx8 xo;
        float sq[8];
        float s = 0.f;
#pragma unroll
        for (int j = 0; j < 8; j++) {
            xo[j] = (short)f2bf(v[j]);
            sq[j] = v[j] * v[j];
            s += sq[j];
        }
        *(shortx8*)(xb + base) = xo;
        int p0 = __builtin_amdgcn_cvt_pk_fp8_f32(sq[0], sq[1], 0, false);
        p0 = __builtin_amdgcn_cvt_pk_fp8_f32(sq[2], sq[3], p0, true);
        int p1 = __builtin_amdgcn_cvt_pk_fp8_f32(sq[4], sq[5], 0, false);
        p1 = __builtin_amdgcn_cvt_pk_fp8_f32(sq[6], sq[7], p1, true);
        int2 pv = {p0, p1};
        *(int2*)(p8 + base) = pv;
        for (int off = 32; off > 0; off >>= 1) s += __shfl_down(s, off, 64);
        if ((threadIdx.x & 63) == 0) atomicAdd(&sumsq[base >> 12], s);
    } else {
        bid -= 4096;
        size_t base = ((size_t)bid * 512 + threadIdx.x) * 8;
        const float4* wp = (const float4*)(W + base);
        const float4* ap = (const float4*)(alpha + base);
        float4 w0 = wp[0], w1 = wp[1], a0 = ap[0], a1 = ap[1];
        float wv[8] = {w0.x, w0.y, w0.z, w0.w, w1.x, w1.y, w1.z, w1.w};
        float av[8] = {a0.x, a0.y, a0.z, a0.w, a1.x, a1.y, a1.z, a1.w};
        shortx8 wo;
        float sg[8];
#pragma unroll
        for (int j = 0; j < 8; j++) {
            wo[j] = (short)f2bf(wv[j]);
            sg[j] = 1.0f / (1.0f + __expf(-av[j]));
        }
        *(shortx8*)(wb + base) = wo;
        int p0 = __builtin_amdgcn_cvt_pk_fp8_f32(sg[0], sg[1], 0, false);
        p0 = __builtin_amdgcn_cvt_pk_fp8_f32(sg[2], sg[3], p0, true);
        int p1 = __builtin_amdgcn_cvt_pk_fp8_f32(sg[4], sg[5], 0, false);
        p1 = __builtin_amdgcn_cvt_pk_fp8_f32(sg[6], sg[7], p1, true);
        int2 pv = {p0, p1};
        *(int2*)(a8 + base) = pv;
    }
}

// ---------- fused dual-GEMM, 3-phase / 2-barrier counted-vmcnt schedule ----------
// bf16 LDS rows 128B, 16B-chunk swizzle kc' = kc ^ (row&7) (2-way = free).
// fp8 LDS rows 64B, 8B-slot swizzle slot' = slot ^ (row&6); b128 reads the
// slot PAIR (2q)^(r&6) -> global chunks (2q,2q+1) in order (r&6 even).
// All staged via pre-swizzled GLOBAL source; LDS dest stays linear.
__global__ __launch_bounds__(512, 2) void fused_gemm_kernel(
    const unsigned short* __restrict__ X,
    const unsigned short* __restrict__ Wb,
    const unsigned char* __restrict__ P8,
    const unsigned char* __restrict__ A8,
    const float* __restrict__ bias,
    const float* __restrict__ eta_p,
    const float* __restrict__ sumsq,
    float* __restrict__ out) {
    constexpr int K = MAT_N;
    constexpr int N = MAT_N;
    __shared__ __align__(16) unsigned short sX[2][256 * 64];  // 64 KB
    __shared__ __align__(16) unsigned short sW[2][128 * 64];  // 32 KB
    __shared__ __align__(16) unsigned char  sP[2][256 * 64];  // 32 KB
    __shared__ __align__(16) unsigned char  sA[2][128 * 64];  // 16 KB

    const int tid = threadIdx.x;
    const int row0 = blockIdx.y * 256;   // identity map (R17 swizzle reverted:
    const int col0 = blockIdx.x * 128;   //  FETCH 251->427MB, default order wins)
    const int lane = tid & 63;
    const int wave = tid >> 6;           // 0..7
    const int wm = (wave >> 1) * 64;     // 4x2 wave grid: 64-row x 64-col each
    const int wn = (wave & 1) * 64;
    const int quad = lane >> 4;
    const int l16 = lane & 15;

    floatx4 accY[4][4], accS[4][4];
#pragma unroll
    for (int i = 0; i < 4; i++)
#pragma unroll
        for (int j = 0; j < 4; j++) {
            accY[i][j] = (floatx4){0.f, 0.f, 0.f, 0.f};
            accS[i][j] = (floatx4){0.f, 0.f, 0.f, 0.f};
        }

    // bf16 staging: per 64-row segment, thread t -> row t>>3, chunk (t&7)^(row&7)
    const int rs  = tid >> 3;
    const int kcg = (tid & 7) ^ (rs & 7);
    const size_t xrow = (size_t)(row0 + rs) * K + (size_t)kcg * 8;
    const size_t wrow = (size_t)(col0 + rs) * K + (size_t)kcg * 8;
    // fp8 staging: per 128-row segment, thread t -> row t>>2, slot (2(t&3))^(row&6)
    const int r8 = tid >> 2;
    const int s8 = (2 * (tid & 3)) ^ (r8 & 6);
    const size_t prow = (size_t)(row0 + r8) * K + (size_t)s8 * 8;
    const size_t arow = (size_t)(col0 + r8) * K + (size_t)s8 * 8;

    const unsigned sx0 = lds_off(&sX[0][0]);
    const unsigned sw0 = lds_off(&sW[0][0]);
    const unsigned sp0 = lds_off(&sP[0][0]);
    const unsigned sa0 = lds_off(&sA[0][0]);

#define PF_X(SEG, BUF, KP) gload_lds16(X + xrow + (size_t)(SEG) * 64 * K + (KP), &sX[BUF][(SEG) * 4096 + tid * 8])
#define PF_W(SEG, BUF, KP) gload_lds16(Wb + wrow + (size_t)(SEG) * 64 * K + (KP), &sW[BUF][(SEG) * 4096 + tid * 8])
#define PF_P(SEG, BUF, KP) gload_lds16(P8 + prow + (size_t)(SEG) * 128 * K + (KP), &sP[BUF][(SEG) * 8192 + tid * 16])
#define PF_A8(BUF, KP)     gload_lds16(A8 + arow + (KP), &sA[BUF][tid * 16])

    // prologue: stage K-step 0 into buf 0 (6 bf16, then 3 fp8)
    PF_X(0, 0, 0); PF_X(1, 0, 0); PF_X(2, 0, 0); PF_X(3, 0, 0);
    PF_W(0, 0, 0); PF_W(1, 0, 0);
    PF_P(0, 0, 0); PF_P(1, 0, 0); PF_A8(0, 0);
    VMCNT(3);          // bf16-0 landed; fp8-0 stays in flight (drained @ph1)
    BARRIER();

    for (int t = 0; t < 64; ++t) {
        const int cur = t & 1;
        const int nx = cur ^ 1;
        const size_t kp = (size_t)((t + 1) & 63) * 64;  // wrap keeps counts uniform
        const unsigned sxc = sx0 + (unsigned)cur * (256 * 64 * 2);
        const unsigned swc = sw0 + (unsigned)cur * (128 * 64 * 2);
        const unsigned spc = sp0 + (unsigned)cur * (256 * 64);
        const unsigned sac = sa0 + (unsigned)cur * (128 * 64);

        // ---------------- ph0: Y . slice0 (no trailing barrier) ----------------
        {
            const unsigned kcp = (unsigned)(((0 * 4 + quad) ^ (l16 & 7)) * 16);
            const unsigned ax = sxc + (unsigned)(wm + l16) * 128 + kcp;
            const unsigned bx = swc + (unsigned)(wn + l16) * 128 + kcp;
            intx4 a[4], b[4];
            a[0] = ldsb128<0>(ax); a[1] = ldsb128<2048>(ax);
            a[2] = ldsb128<4096>(ax); a[3] = ldsb128<6144>(ax);
            b[0] = ldsb128<0>(bx); b[1] = ldsb128<2048>(bx);
            b[2] = ldsb128<4096>(bx); b[3] = ldsb128<6144>(bx);
            PF_X(0, nx, kp); PF_X(1, nx, kp); PF_X(2, nx, kp);
            LGKM0();
            __builtin_amdgcn_s_setprio(1);
#pragma unroll
            for (int i = 0; i < 4; ++i)
#pragma unroll
                for (int j = 0; j < 4; ++j)
                    accY[i][j] = __builtin_amdgcn_mfma_f32_16x16x32_bf16(
                        __builtin_bit_cast(shortx8, a[i]),
                        __builtin_bit_cast(shortx8, b[j]), accY[i][j], 0, 0, 0);
            __builtin_amdgcn_s_setprio(0);
        }
        // ---------------- ph1: Y . slice1 ----------------
        {
            const unsigned kcp = (unsigned)(((1 * 4 + quad) ^ (l16 & 7)) * 16);
            const unsigned ax = sxc + (unsigned)(wm + l16) * 128 + kcp;
            const unsigned bx = swc + (unsigned)(wn + l16) * 128 + kcp;
            intx4 a[4], b[4];
            a[0] = ldsb128<0>(ax); a[1] = ldsb128<2048>(ax);
            a[2] = ldsb128<4096>(ax); a[3] = ldsb128<6144>(ax);
            b[0] = ldsb128<0>(bx); b[1] = ldsb128<2048>(bx);
            b[2] = ldsb128<4096>(bx); b[3] = ldsb128<6144>(bx);
            PF_X(3, nx, kp); PF_W(0, nx, kp); PF_W(1, nx, kp);
            LGKM0();
            __builtin_amdgcn_s_setprio(1);
#pragma unroll
            for (int i = 0; i < 4; ++i)
#pragma unroll
                for (int j = 0; j < 4; ++j)
                    accY[i][j] = __builtin_amdgcn_mfma_f32_16x16x32_bf16(
                        __builtin_bit_cast(shortx8, a[i]),
                        __builtin_bit_cast(shortx8, b[j]), accY[i][j], 0, 0, 0);
            __builtin_amdgcn_s_setprio(0);
            VMCNT(6);   // drains fp8-t (oldest 3); leaves bf16-(t+1) in flight
            BARRIER();
        }
        // ---------------- phS: S paired k-chunks (8 b128, 32 fp8 MFMA) ---------
        {
            const unsigned psw = (unsigned)(((2 * quad) ^ (l16 & 6)) * 8);
            const unsigned px = spc + (unsigned)(wm + l16) * 64 + psw;
            const unsigned qx = sac + (unsigned)(wn + l16) * 64 + psw;
            intx4 p[4], q[4];
            p[0] = ldsb128<0>(px); p[1] = ldsb128<1024>(px);
            p[2] = ldsb128<2048>(px); p[3] = ldsb128<3072>(px);
            q[0] = ldsb128<0>(qx); q[1] = ldsb128<1024>(qx);
            q[2] = ldsb128<2048>(qx); q[3] = ldsb128<3072>(qx);
            PF_P(0, nx, kp); PF_P(1, nx, kp); PF_A8(nx, kp);
            LGKM0();
            __builtin_amdgcn_s_setprio(1);
#pragma unroll
            for (int i = 0; i < 4; ++i) {
                const longx2 pv = __builtin_bit_cast(longx2, p[i]);
#pragma unroll
                for (int j = 0; j < 4; ++j) {
                    const longx2 qv = __builtin_bit_cast(longx2, q[j]);
                    accS[i][j] = __builtin_amdgcn_mfma_f32_16x16x32_fp8_fp8(
                        pv.x, qv.x, accS[i][j], 0, 0, 0);
                    accS[i][j] = __builtin_amdgcn_mfma_f32_16x16x32_fp8_fp8(
                        pv.y, qv.y, accS[i][j], 0, 0, 0);
                }
            }
            __builtin_amdgcn_s_setprio(0);
            VMCNT(3);   // drains bf16-(t+1); leaves fp8-(t+1) in flight
            BARRIER();
        }
    }
    VMCNT(0);   // drain the wrapped tail prefetches before epilogue

    const float eta = *eta_p;
#pragma unroll
    for (int i = 0; i < 4; i++) {
#pragma unroll
        for (int r = 0; r < 4; r++) {
            const int grow = row0 + wm + i * 16 + quad * 4 + r;
            const float invn = 1.0f / (sqrtf(sumsq[grow]) + 1e-8f);
#pragma unroll
            for (int j = 0; j < 4; j++) {
                // C/D layout: row = quad*4 + r, col = lane&15  [m89/m91 verified]
                const int gcol = col0 + wn + j * 16 + l16;
                float y = accY[i][j][r] + bias[gcol];
                float s = accS[i][j][r] * invn;
                out[(size_t)grow * N + gcol] = y + eta * tanhf(y) * s;
            }
        }
    }
}

extern "C" void kernel_launch(void* const* d_in, const int* in_sizes, int n_in,
                              void* d_out, int out_size, void* d_ws, size_t ws_size,
                              hipStream_t stream) {
    const float* x     = (const float*)d_in[0];
    const float* W     = (const float*)d_in[1];
    const float* alpha = (const float*)d_in[2];
    const float* eta   = (const float*)d_in[3];
    const float* bias  = (const float*)d_in[4];
    float* out = (float*)d_out;

    // ws: sumsq f32[4096] (16KB pad) | xb 32MB | wb 32MB | p8 16MB | a8 16MB
    char* ws = (char*)d_ws;
    float* sumsq = (float*)ws;
    unsigned short* xb = (unsigned short*)(ws + 16384);
    unsigned short* wb = xb + MAT_ELEMS;
    unsigned char*  p8 = (unsigned char*)(wb + MAT_ELEMS);
    unsigned char*  a8 = p8 + MAT_ELEMS;

    hipMemsetAsync(sumsq, 0, MAT_N * sizeof(float), stream);
    conv_kernel<<<8192, 512, 0, stream>>>(x, W, alpha, xb, p8, wb, a8, sumsq);

    dim3 grid(MAT_N / 128, MAT_N / 256);   // (N-tiles, M-tiles) = (32, 16)
    fused_gemm_kernel<<<grid, 512, 0, stream>>>(xb, wb, p8, a8, bias, eta, sumsq, out);
}